// Round 8
// baseline (266.111 us; speedup 1.0000x reference)
//
#include <hip/hip_runtime.h>
#include <math.h>

#define POOL 7
#define NCELL 49
#define NCH 256
#define CH_SPLIT 8            // 8000 blocks; 32 ch/block, 8 ch/wave
#define CHPB (NCH / CH_SPLIT)
#define CHPW (CHPB / 4)
#define LDSF 640              // floats per wave window buffer
#define NIT_S 10              // scalar fallback staging iters: 10*64 = 640
#define NBUCK 512             // sort buckets: level(2b)|batch(1b)|qy(3b)|qx(3b)

typedef float f32x2 __attribute__((ext_vector_type(2)));

typedef __attribute__((address_space(1))) void global_void;
typedef __attribute__((address_space(3))) void lds_void;
__device__ __forceinline__ void stage4(const float* g, float* l) {
    __builtin_amdgcn_global_load_lds((global_void*)g, (lds_void*)l, 4, 0, 0);
}
__device__ __forceinline__ void stage16(const float* g, float* l) {
    __builtin_amdgcn_global_load_lds((global_void*)g, (lds_void*)l, 16, 0, 0);
}
__device__ __forceinline__ unsigned ldsaddr(const float* p) {
    // generic -> AS3 -> 32-bit LDS byte offset (AS3 pointers are 32-bit)
    return (unsigned)(uintptr_t)(lds_void*)(void*)const_cast<float*>(p);
}

template <int V> __device__ __forceinline__ void vwait() {
    if constexpr (V == 0)  asm volatile("s_waitcnt vmcnt(0)" ::: "memory");
    else if constexpr (V == 1)  asm volatile("s_waitcnt vmcnt(1)" ::: "memory");
    else if constexpr (V == 2)  asm volatile("s_waitcnt vmcnt(2)" ::: "memory");
    else if constexpr (V == 3)  asm volatile("s_waitcnt vmcnt(3)" ::: "memory");
    else if constexpr (V == 4)  asm volatile("s_waitcnt vmcnt(4)" ::: "memory");
    else if constexpr (V == 6)  asm volatile("s_waitcnt vmcnt(6)" ::: "memory");
    else if constexpr (V == 10) asm volatile("s_waitcnt vmcnt(10)" ::: "memory");
    else if constexpr (V == 20) asm volatile("s_waitcnt vmcnt(20)" ::: "memory");
}

struct Tab {
    int loff0[4], loff1[4];
    float w00[4], w01[4], w10[4], w11[4];
};

__device__ __forceinline__ void make_tab(Tab& tb, int lane, int W, int rs, int xb, int y0,
                                         float x1, float y1, float bin_w, float bin_h)
{
    int cell = (lane < NCELL) ? lane : (NCELL - 1);
    int py = cell / POOL, px = cell % POOL;
#pragma unroll
    for (int s = 0; s < 4; ++s) {
        int sy = s >> 1, sx = s & 1;
        float y = y1 + bin_h * ((float)py + ((float)sy + 0.5f) * 0.5f);
        float x = x1 + bin_w * ((float)px + ((float)sx + 0.5f) * 0.5f);
        bool v = (y > -1.f) && (y < (float)W) && (x > -1.f) && (x < (float)W);
        float yc = fminf(fmaxf(y, 0.f), (float)(W - 1));
        float xc = fminf(fmaxf(x, 0.f), (float)(W - 1));
        int ylo = (int)floorf(yc), xlo = (int)floorf(xc);
        int yhi = min(ylo + 1, W - 1);
        float fy = yc - (float)ylo, fx = xc - (float)xlo;
        float vv = v ? 0.25f : 0.f;            // validity + 1/(SR*SR)
        int bxp = min(xlo, W - 2);             // keep float-pair in-row
        bool in = (xlo == bxp);
        float wx0 = in ? (1.f - fx) : 0.f;
        float wx1 = in ? fx : 1.f;
        float wr0 = (1.f - fy) * vv, wr1 = fy * vv;
        tb.loff0[s] = (ylo - y0) * rs + (bxp - xb);
        tb.loff1[s] = (yhi - y0) * rs + (bxp - xb);
        tb.w00[s] = wr0 * wx0; tb.w01[s] = wr0 * wx1;
        tb.w10[s] = wr1 * wx0; tb.w11[s] = wr1 * wx1;
    }
}

// Consume: 8x ds_read2_b32 (one per tap-pair) instead of 16x ds_read_b32 --
// halves LDS-pipe issue slots, the measured ~65%-utilized resource. Only
// 4B alignment required (works for padded wwa and packed ww layouts).
// Rule-18 discipline: issue all reads, one lgkmcnt(0), sched_barrier(0),
// then FMAs (compiler can't hoist them above the wait).
__device__ __forceinline__ float consume(const float* cb, const Tab& tb)
{
    unsigned base = ldsaddr(cb);
    f32x2 p0[4], p1[4];
#pragma unroll
    for (int s = 0; s < 4; ++s) {
        unsigned a0 = base + 4u * (unsigned)tb.loff0[s];
        unsigned a1 = base + 4u * (unsigned)tb.loff1[s];
        asm volatile("ds_read2_b32 %0, %1 offset0:0 offset1:1" : "=v"(p0[s]) : "v"(a0));
        asm volatile("ds_read2_b32 %0, %1 offset0:0 offset1:1" : "=v"(p1[s]) : "v"(a1));
    }
    asm volatile("s_waitcnt lgkmcnt(0)" ::: "memory");
    __builtin_amdgcn_sched_barrier(0);
    float acc = 0.f;
#pragma unroll
    for (int s = 0; s < 4; ++s) {
        acc += tb.w00[s] * p0[s].x + tb.w01[s] * p0[s].y
             + tb.w10[s] * p1[s].x + tb.w11[s] * p1[s].y;
    }
    return acc;
}

// ---- x4 path: depth-2 prefetch over 3 wave-private LDS buffers ----
// Store discipline (r2/r6-proven, keeps WRITE_SIZE ~67MB): steady-state
// vmcnt(2*NIT4) drains loads_i AND store_{i-1}; at most one store in
// flight. Do NOT exclude stores from waits (r3 +78MB / r5 +710MB).
template <int NIT4>
__device__ __forceinline__ void box_x4(
    const float* fbase, float* outp, float* sm, int lane,
    int W, int HW, int wwa, int y0, int x0a, int ngrp,
    float x1, float y1, float bin_w, float bin_h)
{
    int g_off[NIT4];
    bool act[NIT4];
    int wwa4 = wwa >> 2;
#pragma unroll
    for (int k = 0; k < NIT4; ++k) {
        int idx = k * 64 + lane;
        act[k] = idx < ngrp;
        int ii = act[k] ? idx : 0;
        int r = ii / wwa4;
        int c = ii - r * wwa4;
        g_off[k] = (y0 + r) * W + x0a + c * 4;   // 16B-aligned (W%4==0, x0a%4==0)
    }
    // prologue: ch0 -> buf0, ch1 -> buf1
#pragma unroll
    for (int k = 0; k < NIT4; ++k)
        if (act[k]) stage16(fbase + g_off[k], sm + k * 256);
#pragma unroll
    for (int k = 0; k < NIT4; ++k)
        if (act[k]) stage16(fbase + (size_t)HW + g_off[k], sm + LDSF + k * 256);

    Tab tb;
    make_tab(tb, lane, W, wwa, x0a, y0, x1, y1, bin_w, bin_h);

#pragma unroll                                   // FULL unroll: %3 goes static
    for (int i = 0; i < CHPW; ++i) {
        if (i + 2 < CHPW) {
            const float* fc = fbase + (size_t)(i + 2) * HW;
            float* nb = sm + ((i + 2) % 3) * LDSF;
#pragma unroll
            for (int k = 0; k < NIT4; ++k)
                if (act[k]) stage16(fc + g_off[k], nb + k * 256);
            vwait<2 * NIT4>();
        } else if (i + 1 < CHPW) {
            vwait<NIT4>();
        } else {
            vwait<1>();
        }
        float acc = consume(sm + (i % 3) * LDSF, tb);
        if (lane < NCELL)
            __builtin_nontemporal_store(acc, outp + (size_t)i * NCELL);
    }
}

// ---- scalar fallback for rare oversized padded windows (same schedule) ----
__device__ __forceinline__ void box_s(
    const float* fbase, float* outp, float* sm, int lane,
    int W, int HW, int ww, int y0, int x0, int packed,
    float x1, float y1, float bin_w, float bin_h)
{
    int g_off[NIT_S];
#pragma unroll
    for (int k = 0; k < NIT_S; ++k) {
        int idx = k * 64 + lane;
        idx = (idx < packed) ? idx : 0;
        int r = idx / ww;
        int c = idx - r * ww;
        g_off[k] = (y0 + r) * W + (x0 + c);
    }
#pragma unroll
    for (int k = 0; k < NIT_S; ++k) stage4(fbase + g_off[k], sm + k * 64);
#pragma unroll
    for (int k = 0; k < NIT_S; ++k) stage4(fbase + (size_t)HW + g_off[k], sm + LDSF + k * 64);

    Tab tb;
    make_tab(tb, lane, W, ww, x0, y0, x1, y1, bin_w, bin_h);

#pragma unroll
    for (int i = 0; i < CHPW; ++i) {
        if (i + 2 < CHPW) {
            const float* fc = fbase + (size_t)(i + 2) * HW;
            float* nb = sm + ((i + 2) % 3) * LDSF;
#pragma unroll
            for (int k = 0; k < NIT_S; ++k) stage4(fc + g_off[k], nb + k * 64);
            vwait<20>();
        } else if (i + 1 < CHPW) {
            vwait<10>();
        } else {
            vwait<1>();
        }
        float acc = consume(sm + (i % 3) * LDSF, tb);
        if (lane < NCELL)
            __builtin_nontemporal_store(acc, outp + (size_t)i * NCELL);
    }
}

// ---- box ordering: counting sort by (level, batch, 8x8 center bucket) ----
// Concurrent blocks then work on same-level spatially-adjacent boxes, so
// overlapping windows hit in L2 (FETCH 171->58 MB measured). Output values
// are independent of processing order -> any permutation exact.
__device__ __forceinline__ int box_key(const float* boxes, const int* bidx, int n)
{
    float bx1 = boxes[4 * n + 0], by1 = boxes[4 * n + 1];
    float bx2 = boxes[4 * n + 2], by2 = boxes[4 * n + 3];
    float area = (by2 - by1) * (bx2 - bx1);
    float lvlf = logf(sqrtf(area)) * 1.4426950408889634f;
    int level = (int)fminf(fmaxf(rintf(lvlf) + 4.0f, 0.0f), 3.0f);
    int b = bidx[n] & 1;
    float cx = 0.5f * (bx1 + bx2), cy = 0.5f * (by1 + by2);
    int qx = min(7, max(0, (int)(cx * 8.0f)));
    int qy = min(7, max(0, (int)(cy * 8.0f)));
    return (((((level << 1) | b) << 3) | qy) << 3) | qx;   // < NBUCK
}

__global__ __launch_bounds__(NBUCK) void box_sort_kernel(
    const float* __restrict__ boxes, const int* __restrict__ bidx,
    int* __restrict__ perm, int N)
{
    __shared__ int h0[NBUCK], h1[NBUCK];
    const int t = threadIdx.x;
    h0[t] = 0;
    __syncthreads();
    for (int n = t; n < N; n += NBUCK)
        atomicAdd(&h0[box_key(boxes, bidx, n)], 1);
    __syncthreads();
    int* src = h0; int* dst = h1;
    for (int off = 1; off < NBUCK; off <<= 1) {
        dst[t] = src[t] + ((t >= off) ? src[t - off] : 0);
        __syncthreads();
        int* tmp = src; src = dst; dst = tmp;
    }
    dst[t] = (t == 0) ? 0 : src[t - 1];   // exclusive base
    __syncthreads();
    for (int n = t; n < N; n += NBUCK) {
        int slot = atomicAdd(&dst[box_key(boxes, bidx, n)], 1);
        perm[slot] = n;
    }
}

// grid(8, N): linear id = c + 8*n -> XCD = c (round-robin heuristic), so each
// channel slice's cross-box window overlap stays in ONE XCD's L2.
__global__ __launch_bounds__(256, 5) void roi_align_fpn_kernel(
    const float* __restrict__ p2, const float* __restrict__ p3,
    const float* __restrict__ p4, const float* __restrict__ p5,
    const float* __restrict__ boxes, const int* __restrict__ bidx,
    const int* __restrict__ perm,
    float* __restrict__ out, int N)
{
    __shared__ float smem[4][3][LDSF];   // 30720 B -> 5 blocks/CU (depth-2 pipe)
    const int n = perm ? perm[blockIdx.y] : (int)blockIdx.y;
    const int t = threadIdx.x;
    const int wave = t >> 6;
    const int lane = t & 63;

    // ---- per-box params (block-uniform) ----
    float bx1 = boxes[4 * n + 0], by1 = boxes[4 * n + 1];
    float bx2 = boxes[4 * n + 2], by2 = boxes[4 * n + 3];
    float area = (by2 - by1) * (bx2 - bx1);
    float lvlf = logf(sqrtf(area)) * 1.4426950408889634f; // log2(sqrt(area))
    int level = (int)fminf(fmaxf(rintf(lvlf) + 4.0f, 0.0f), 3.0f);
    int W = 256 >> level;        // square levels
    int HW = W * W;
    float scale = (float)W;
    float x1 = bx1 * scale, y1 = by1 * scale;
    float bin_w = fmaxf((bx2 - bx1) * scale, 1.0f) * (1.0f / POOL);
    float bin_h = fmaxf((by2 - by1) * scale, 1.0f) * (1.0f / POOL);

    const float* feat = (level == 0) ? p2 : (level == 1) ? p3 : (level == 2) ? p4 : p5;
    feat += (size_t)bidx[n] * NCH * HW;

    // ---- window bounds (block-uniform; samples are monotonic in py/px) ----
    float yA = y1 + bin_h * 0.25f, yB = y1 + bin_h * 6.75f;
    float xA = x1 + bin_w * 0.25f, xB = x1 + bin_w * 6.75f;
    int y0  = (int)floorf(fminf(fmaxf(yA, 0.f), (float)(W - 1)));
    int y1h = min((int)floorf(fminf(fmaxf(yB, 0.f), (float)(W - 1))) + 1, W - 1);
    int x0  = (int)floorf(fminf(fmaxf(xA, 0.f), (float)(W - 1)));
    x0 = min(x0, W - 2);                       // pair base can be one left of first xlo
    int x1p = min((int)floorf(fminf(fmaxf(xB, 0.f), (float)(W - 1))) + 1, W - 1);
    int ww = x1p - x0 + 1;
    int wh = y1h - y0 + 1;

    // padded 4-aligned window for the x4 path.
    // Bank-stride rule: wwa%8==0 makes rows alias every <=4 rows on 32 banks;
    // +4 (gcd(wwa,32)=4) pushes aliasing to 8 rows apart. Space-permitting.
    int x0a = x0 & ~3;
    int wwa = ((x1p - x0a + 1) + 3) & ~3;
    if ((wwa & 7) == 0 && (wwa + 4) * wh <= LDSF) wwa += 4;
    int padded = wwa * wh;

    const int ch0 = blockIdx.x * CHPB + wave * CHPW;
    const float* fbase = feat + (size_t)ch0 * HW;
    float* sm = &smem[wave][0][0];
    int cell = (lane < NCELL) ? lane : (NCELL - 1);
    float* outp = out + (size_t)n * NCH * NCELL + (size_t)ch0 * NCELL + cell;

    if (padded <= LDSF) {
        int ngrp = (wwa >> 2) * wh;            // <= 160
        int nit4 = (ngrp + 63) >> 6;           // in {1,2,3}
        if (nit4 == 1)      box_x4<1>(fbase, outp, sm, lane, W, HW, wwa, y0, x0a, ngrp, x1, y1, bin_w, bin_h);
        else if (nit4 == 2) box_x4<2>(fbase, outp, sm, lane, W, HW, wwa, y0, x0a, ngrp, x1, y1, bin_w, bin_h);
        else                box_x4<3>(fbase, outp, sm, lane, W, HW, wwa, y0, x0a, ngrp, x1, y1, bin_w, bin_h);
    } else {
        int whc = min(wh, LDSF / ww);          // provably a no-op; memory-safety clamp
        int packed = ww * whc;
        box_s(fbase, outp, sm, lane, W, HW, ww, y0, x0, packed, x1, y1, bin_w, bin_h);
    }
}

extern "C" void kernel_launch(void* const* d_in, const int* in_sizes, int n_in,
                              void* d_out, int out_size, void* d_ws, size_t ws_size,
                              hipStream_t stream) {
    const float* p2    = (const float*)d_in[0];
    const float* p3    = (const float*)d_in[1];
    const float* p4    = (const float*)d_in[2];
    const float* p5    = (const float*)d_in[3];
    const float* boxes = (const float*)d_in[4];
    const int*   bidx  = (const int*)d_in[5];
    float* out = (float*)d_out;
    int N = in_sizes[5];
    int* perm = nullptr;
    if (d_ws && ws_size >= (size_t)N * sizeof(int)) {
        perm = (int*)d_ws;
        box_sort_kernel<<<1, NBUCK, 0, stream>>>(boxes, bidx, perm, N);
    }
    dim3 grid(CH_SPLIT, N);
    roi_align_fpn_kernel<<<grid, 256, 0, stream>>>(p2, p3, p4, p5, boxes, bidx, perm, out, N);
}

// Round 9
// 261.874 us; speedup vs baseline: 1.0162x; 1.0162x over previous
//
#include <hip/hip_runtime.h>
#include <math.h>

#define POOL 7
#define NCELL 49
#define NCH 256
#define CH_SPLIT 8            // 8000 blocks; 32 ch/block, 8 ch/wave
#define CHPB (NCH / CH_SPLIT)
#define CHPW (CHPB / 4)       // 8 channels per wave, processed as 4 pairs
#define LDSF 640              // floats per channel window slot
#define NIT_S 10              // scalar fallback staging iters: 10*64 = 640
#define NBUCK 512             // sort buckets: level(2b)|batch(1b)|qy(3b)|qx(3b)

typedef float f32x2 __attribute__((ext_vector_type(2)));

typedef __attribute__((address_space(1))) void global_void;
typedef __attribute__((address_space(3))) void lds_void;
__device__ __forceinline__ void stage4(const float* g, float* l) {
    __builtin_amdgcn_global_load_lds((global_void*)g, (lds_void*)l, 4, 0, 0);
}
__device__ __forceinline__ void stage16(const float* g, float* l) {
    __builtin_amdgcn_global_load_lds((global_void*)g, (lds_void*)l, 16, 0, 0);
}
__device__ __forceinline__ unsigned ldsaddr(const float* p) {
    return (unsigned)(uintptr_t)(lds_void*)(void*)const_cast<float*>(p);
}

template <int V> __device__ __forceinline__ void vwait() {
    if constexpr (V == 0)  asm volatile("s_waitcnt vmcnt(0)" ::: "memory");
    else if constexpr (V == 2)  asm volatile("s_waitcnt vmcnt(2)" ::: "memory");
    else if constexpr (V == 4)  asm volatile("s_waitcnt vmcnt(4)" ::: "memory");
    else if constexpr (V == 6)  asm volatile("s_waitcnt vmcnt(6)" ::: "memory");
    else if constexpr (V == 8)  asm volatile("s_waitcnt vmcnt(8)" ::: "memory");
    else if constexpr (V == 20) asm volatile("s_waitcnt vmcnt(20)" ::: "memory");
    else if constexpr (V == 22) asm volatile("s_waitcnt vmcnt(22)" ::: "memory");
}

struct Tab {
    int loff0[4], loff1[4];
    float w00[4], w01[4], w10[4], w11[4];
};

__device__ __forceinline__ void make_tab(Tab& tb, int lane, int W, int rs, int xb, int y0,
                                         float x1, float y1, float bin_w, float bin_h)
{
    int cell = (lane < NCELL) ? lane : (NCELL - 1);
    int py = cell / POOL, px = cell % POOL;
#pragma unroll
    for (int s = 0; s < 4; ++s) {
        int sy = s >> 1, sx = s & 1;
        float y = y1 + bin_h * ((float)py + ((float)sy + 0.5f) * 0.5f);
        float x = x1 + bin_w * ((float)px + ((float)sx + 0.5f) * 0.5f);
        bool v = (y > -1.f) && (y < (float)W) && (x > -1.f) && (x < (float)W);
        float yc = fminf(fmaxf(y, 0.f), (float)(W - 1));
        float xc = fminf(fmaxf(x, 0.f), (float)(W - 1));
        int ylo = (int)floorf(yc), xlo = (int)floorf(xc);
        int yhi = min(ylo + 1, W - 1);
        float fy = yc - (float)ylo, fx = xc - (float)xlo;
        float vv = v ? 0.25f : 0.f;            // validity + 1/(SR*SR)
        int bxp = min(xlo, W - 2);             // keep float-pair in-row
        bool in = (xlo == bxp);
        float wx0 = in ? (1.f - fx) : 0.f;
        float wx1 = in ? fx : 1.f;
        float wr0 = (1.f - fy) * vv, wr1 = fy * vv;
        tb.loff0[s] = (ylo - y0) * rs + (bxp - xb);
        tb.loff1[s] = (yhi - y0) * rs + (bxp - xb);
        tb.w00[s] = wr0 * wx0; tb.w01[s] = wr0 * wx1;
        tb.w10[s] = wr1 * wx0; tb.w11[s] = wr1 * wx1;
    }
}

// 8x ds_read2_b32 (tap pairs); rule-18: one lgkmcnt(0)+sched_barrier, then FMAs.
__device__ __forceinline__ float consume(const float* cb, const Tab& tb)
{
    unsigned base = ldsaddr(cb);
    f32x2 p0[4], p1[4];
#pragma unroll
    for (int s = 0; s < 4; ++s) {
        unsigned a0 = base + 4u * (unsigned)tb.loff0[s];
        unsigned a1 = base + 4u * (unsigned)tb.loff1[s];
        asm volatile("ds_read2_b32 %0, %1 offset0:0 offset1:1" : "=v"(p0[s]) : "v"(a0));
        asm volatile("ds_read2_b32 %0, %1 offset0:0 offset1:1" : "=v"(p1[s]) : "v"(a1));
    }
    asm volatile("s_waitcnt lgkmcnt(0)" ::: "memory");
    __builtin_amdgcn_sched_barrier(0);
    float acc = 0.f;
#pragma unroll
    for (int s = 0; s < 4; ++s) {
        acc += tb.w00[s] * p0[s].x + tb.w01[s] * p0[s].y
             + tb.w10[s] * p1[s].x + tb.w11[s] * p1[s].y;
    }
    return acc;
}

// ---- x4 path: PAIR pipeline -- one vmcnt rendezvous per 2 channels ----
// Motivation (r6/r7/r8): per-SIMD iteration-slot cost is ~860cy regardless of
// occupancy, depth, or instruction count -> the per-iteration wait itself is
// the floor. Halve the number of waits (4/wave instead of 8) and double the
// work issued per wait.
// Stores are REGULAR (cached): partial-line merging happens in L2 write-back,
// so no ack discipline is needed; stores ride the vmcnt queue with 2-pair
// slack and the wait never blocks on a fresh store ack.
// vmcnt ledger (N=NIT4 loads per channel, 2N per pair; Tpc = store c of pair p):
//   prologue:  S_P0                         -> [L0:2N]
//   it0: S_P1                [L0,L1]         W=2N    drains L0
//        C,T00,C,T01        -> [L1,T00,T01]
//   it1: S_P2                [...,L2]        W=2N+2  drains L1
//        C,T10,C,T11        -> [T00,T01,L2,T10,T11]
//   it2: S_P3                [...,L3]        W=2N+2  drains T00,T01,L2
//        C,T20,C,T21        -> [T10,T11,L3,T20,T21]
//   it3: (no stage)                          W=2     drains T10,T11,L3
template <int NIT4>
__device__ __forceinline__ void box_x4(
    const float* fbase, float* outp, float* sm, int lane,
    int W, int HW, int wwa, int y0, int x0a, int ngrp,
    float x1, float y1, float bin_w, float bin_h)
{
    int g_off[NIT4];
    bool act[NIT4];
    int wwa4 = wwa >> 2;
#pragma unroll
    for (int k = 0; k < NIT4; ++k) {
        int idx = k * 64 + lane;
        act[k] = idx < ngrp;
        int ii = act[k] ? idx : 0;
        int r = ii / wwa4;
        int c = ii - r * wwa4;
        g_off[k] = (y0 + r) * W + x0a + c * 4;   // 16B-aligned (W%4==0, x0a%4==0)
    }
    float* const buf0 = sm;
    float* const buf1 = sm + 2 * LDSF;

    auto do_stage = [&](int pair, float* buf) {
#pragma unroll
        for (int c = 0; c < 2; ++c) {
            const float* fc = fbase + (size_t)(2 * pair + c) * HW;
            float* nb = buf + c * LDSF;
#pragma unroll
            for (int k = 0; k < NIT4; ++k)
                if (act[k]) stage16(fc + g_off[k], nb + k * 256);
        }
    };

    do_stage(0, buf0);                       // prologue

    Tab tb;
    make_tab(tb, lane, W, wwa, x0a, y0, x1, y1, bin_w, bin_h);

    auto do_cons = [&](int pair, const float* buf) {
        float a0 = consume(buf, tb);
        if (lane < NCELL) outp[(size_t)(2 * pair) * NCELL] = a0;       // regular store
        float a1 = consume(buf + LDSF, tb);
        if (lane < NCELL) outp[(size_t)(2 * pair + 1) * NCELL] = a1;   // regular store
    };

    do_stage(1, buf1);  vwait<2 * NIT4>();      do_cons(0, buf0);
    do_stage(2, buf0);  vwait<2 * NIT4 + 2>();  do_cons(1, buf1);
    do_stage(3, buf1);  vwait<2 * NIT4 + 2>();  do_cons(2, buf0);
                        vwait<2>();             do_cons(3, buf1);
}

// ---- scalar fallback for rare oversized padded windows (same pair schedule) ----
__device__ __forceinline__ void box_s(
    const float* fbase, float* outp, float* sm, int lane,
    int W, int HW, int ww, int y0, int x0, int packed,
    float x1, float y1, float bin_w, float bin_h)
{
    int g_off[NIT_S];
#pragma unroll
    for (int k = 0; k < NIT_S; ++k) {
        int idx = k * 64 + lane;
        idx = (idx < packed) ? idx : 0;
        int r = idx / ww;
        int c = idx - r * ww;
        g_off[k] = (y0 + r) * W + (x0 + c);
    }
    float* const buf0 = sm;
    float* const buf1 = sm + 2 * LDSF;

    auto do_stage = [&](int pair, float* buf) {
#pragma unroll
        for (int c = 0; c < 2; ++c) {
            const float* fc = fbase + (size_t)(2 * pair + c) * HW;
            float* nb = buf + c * LDSF;
#pragma unroll
            for (int k = 0; k < NIT_S; ++k) stage4(fc + g_off[k], nb + k * 64);
        }
    };

    do_stage(0, buf0);

    Tab tb;
    make_tab(tb, lane, W, ww, x0, y0, x1, y1, bin_w, bin_h);

    auto do_cons = [&](int pair, const float* buf) {
        float a0 = consume(buf, tb);
        if (lane < NCELL) outp[(size_t)(2 * pair) * NCELL] = a0;
        float a1 = consume(buf + LDSF, tb);
        if (lane < NCELL) outp[(size_t)(2 * pair + 1) * NCELL] = a1;
    };

    do_stage(1, buf1);  vwait<20>();  do_cons(0, buf0);
    do_stage(2, buf0);  vwait<22>();  do_cons(1, buf1);
    do_stage(3, buf1);  vwait<22>();  do_cons(2, buf0);
                        vwait<2>();   do_cons(3, buf1);
}

// ---- box ordering: counting sort by (level, batch, 8x8 center bucket) ----
// (FETCH 171->58 MB measured.) Output independent of order -> exact.
__device__ __forceinline__ int box_key(const float* boxes, const int* bidx, int n)
{
    float bx1 = boxes[4 * n + 0], by1 = boxes[4 * n + 1];
    float bx2 = boxes[4 * n + 2], by2 = boxes[4 * n + 3];
    float area = (by2 - by1) * (bx2 - bx1);
    float lvlf = logf(sqrtf(area)) * 1.4426950408889634f;
    int level = (int)fminf(fmaxf(rintf(lvlf) + 4.0f, 0.0f), 3.0f);
    int b = bidx[n] & 1;
    float cx = 0.5f * (bx1 + bx2), cy = 0.5f * (by1 + by2);
    int qx = min(7, max(0, (int)(cx * 8.0f)));
    int qy = min(7, max(0, (int)(cy * 8.0f)));
    return (((((level << 1) | b) << 3) | qy) << 3) | qx;   // < NBUCK
}

__global__ __launch_bounds__(NBUCK) void box_sort_kernel(
    const float* __restrict__ boxes, const int* __restrict__ bidx,
    int* __restrict__ perm, int N)
{
    __shared__ int h0[NBUCK], h1[NBUCK];
    const int t = threadIdx.x;
    h0[t] = 0;
    __syncthreads();
    for (int n = t; n < N; n += NBUCK)
        atomicAdd(&h0[box_key(boxes, bidx, n)], 1);
    __syncthreads();
    int* src = h0; int* dst = h1;
    for (int off = 1; off < NBUCK; off <<= 1) {
        dst[t] = src[t] + ((t >= off) ? src[t - off] : 0);
        __syncthreads();
        int* tmp = src; src = dst; dst = tmp;
    }
    dst[t] = (t == 0) ? 0 : src[t - 1];   // exclusive base
    __syncthreads();
    for (int n = t; n < N; n += NBUCK) {
        int slot = atomicAdd(&dst[box_key(boxes, bidx, n)], 1);
        perm[slot] = n;
    }
}

// grid(8, N): linear id = c + 8*n -> XCD = c, channel slice pinned to one L2.
__global__ __launch_bounds__(256, 4) void roi_align_fpn_kernel(
    const float* __restrict__ p2, const float* __restrict__ p3,
    const float* __restrict__ p4, const float* __restrict__ p5,
    const float* __restrict__ boxes, const int* __restrict__ bidx,
    const int* __restrict__ perm,
    float* __restrict__ out, int N)
{
    __shared__ float smem[4][2][2 * LDSF];   // 40960 B -> 4 blocks/CU
    const int n = perm ? perm[blockIdx.y] : (int)blockIdx.y;
    const int t = threadIdx.x;
    const int wave = t >> 6;
    const int lane = t & 63;

    // ---- per-box params (block-uniform) ----
    float bx1 = boxes[4 * n + 0], by1 = boxes[4 * n + 1];
    float bx2 = boxes[4 * n + 2], by2 = boxes[4 * n + 3];
    float area = (by2 - by1) * (bx2 - bx1);
    float lvlf = logf(sqrtf(area)) * 1.4426950408889634f; // log2(sqrt(area))
    int level = (int)fminf(fmaxf(rintf(lvlf) + 4.0f, 0.0f), 3.0f);
    int W = 256 >> level;        // square levels
    int HW = W * W;
    float scale = (float)W;
    float x1 = bx1 * scale, y1 = by1 * scale;
    float bin_w = fmaxf((bx2 - bx1) * scale, 1.0f) * (1.0f / POOL);
    float bin_h = fmaxf((by2 - by1) * scale, 1.0f) * (1.0f / POOL);

    const float* feat = (level == 0) ? p2 : (level == 1) ? p3 : (level == 2) ? p4 : p5;
    feat += (size_t)bidx[n] * NCH * HW;

    // ---- window bounds (block-uniform; samples are monotonic in py/px) ----
    float yA = y1 + bin_h * 0.25f, yB = y1 + bin_h * 6.75f;
    float xA = x1 + bin_w * 0.25f, xB = x1 + bin_w * 6.75f;
    int y0  = (int)floorf(fminf(fmaxf(yA, 0.f), (float)(W - 1)));
    int y1h = min((int)floorf(fminf(fmaxf(yB, 0.f), (float)(W - 1))) + 1, W - 1);
    int x0  = (int)floorf(fminf(fmaxf(xA, 0.f), (float)(W - 1)));
    x0 = min(x0, W - 2);                       // pair base can be one left of first xlo
    int x1p = min((int)floorf(fminf(fmaxf(xB, 0.f), (float)(W - 1))) + 1, W - 1);
    int ww = x1p - x0 + 1;
    int wh = y1h - y0 + 1;

    // padded 4-aligned window for the x4 path (+bank-stride rule, r8)
    int x0a = x0 & ~3;
    int wwa = ((x1p - x0a + 1) + 3) & ~3;
    if ((wwa & 7) == 0 && (wwa + 4) * wh <= LDSF) wwa += 4;
    int padded = wwa * wh;

    const int ch0 = blockIdx.x * CHPB + wave * CHPW;
    const float* fbase = feat + (size_t)ch0 * HW;
    float* sm = &smem[wave][0][0];
    int cell = (lane < NCELL) ? lane : (NCELL - 1);
    float* outp = out + (size_t)n * NCH * NCELL + (size_t)ch0 * NCELL + cell;

    if (padded <= LDSF) {
        int ngrp = (wwa >> 2) * wh;            // <= 160
        int nit4 = (ngrp + 63) >> 6;           // in {1,2,3}
        if (nit4 == 1)      box_x4<1>(fbase, outp, sm, lane, W, HW, wwa, y0, x0a, ngrp, x1, y1, bin_w, bin_h);
        else if (nit4 == 2) box_x4<2>(fbase, outp, sm, lane, W, HW, wwa, y0, x0a, ngrp, x1, y1, bin_w, bin_h);
        else                box_x4<3>(fbase, outp, sm, lane, W, HW, wwa, y0, x0a, ngrp, x1, y1, bin_w, bin_h);
    } else {
        int whc = min(wh, LDSF / ww);          // provably a no-op; memory-safety clamp
        int packed = ww * whc;
        box_s(fbase, outp, sm, lane, W, HW, ww, y0, x0, packed, x1, y1, bin_w, bin_h);
    }
}

extern "C" void kernel_launch(void* const* d_in, const int* in_sizes, int n_in,
                              void* d_out, int out_size, void* d_ws, size_t ws_size,
                              hipStream_t stream) {
    const float* p2    = (const float*)d_in[0];
    const float* p3    = (const float*)d_in[1];
    const float* p4    = (const float*)d_in[2];
    const float* p5    = (const float*)d_in[3];
    const float* boxes = (const float*)d_in[4];
    const int*   bidx  = (const int*)d_in[5];
    float* out = (float*)d_out;
    int N = in_sizes[5];
    int* perm = nullptr;
    if (d_ws && ws_size >= (size_t)N * sizeof(int)) {
        perm = (int*)d_ws;
        box_sort_kernel<<<1, NBUCK, 0, stream>>>(boxes, bidx, perm, N);
    }
    dim3 grid(CH_SPLIT, N);
    roi_align_fpn_kernel<<<grid, 256, 0, stream>>>(p2, p3, p4, p5, boxes, bidx, perm, out, N);
}